// Round 1
// baseline (126.807 us; speedup 1.0000x reference)
//
#include <hip/hip_runtime.h>

// Problem constants (fixed by the reference):
#define E_ 16
#define T_ 2048
#define H_ 1024
#define I_ 512
#define K_ 2
#define NPAIR (T_*K_)          // 4096 token-expert pairs, always all routed

// Workspace layout (bytes):
//   [0)                offs[E_+1]           (ints)
//   [1024)             pair_ts[NPAIR]       (ints: t*K_+k packed)
//   [1024+4*NPAIR)     pair_w[NPAIR]        (floats)
//   [1 MiB)            c1[NPAIR][2*I_]      (fp32, 16 MiB)
//   [17 MiB)           act[NPAIR][I_]       (bf16 as ushort, 4 MiB)
// total ~21 MiB

typedef __bf16 bf16x8 __attribute__((ext_vector_type(8)));
typedef float  f32x4  __attribute__((ext_vector_type(4)));

static __device__ __forceinline__ unsigned short f2bf(float f) {
    union { float f; unsigned u; } v; v.f = f;
    unsigned r = v.u + 0x7fffu + ((v.u >> 16) & 1u);   // RNE
    return (unsigned short)(r >> 16);
}

// ---------------- routing: stable counting sort of 4096 pairs by expert ----
__global__ __launch_bounds__(256) void route_kernel(
    const float* __restrict__ tw, const int* __restrict__ ti,
    int* __restrict__ offs, int* __restrict__ pair_ts, float* __restrict__ pair_w)
{
    __shared__ unsigned short hist[256][E_];   // 8 KB
    __shared__ int ebase[E_];
    const int tid = threadIdx.x;

    int e_loc[16];
    unsigned short h[E_];
    for (int e = 0; e < E_; ++e) h[e] = 0;
    for (int i = 0; i < 16; ++i) {
        int p = tid * 16 + i;
        int e = ti[p];
        e_loc[i] = e;
        h[e]++;
    }
    for (int e = 0; e < E_; ++e) hist[tid][e] = h[e];
    __syncthreads();

    if (tid < E_) {            // thread e: exclusive prefix across 256 threads
        int e = tid, run = 0;
        for (int t = 0; t < 256; ++t) {
            unsigned short c = hist[t][e];
            hist[t][e] = (unsigned short)run;
            run += c;
        }
        ebase[e] = run;        // total for expert e
    }
    __syncthreads();
    if (tid == 0) {
        int run = 0;
        for (int e = 0; e < E_; ++e) { int c = ebase[e]; offs[e] = run; ebase[e] = run; run += c; }
        offs[E_] = run;        // == NPAIR
    }
    __syncthreads();

    int cur[E_];
    for (int e = 0; e < E_; ++e) cur[e] = ebase[e] + hist[tid][e];
    for (int i = 0; i < 16; ++i) {
        int p = tid * 16 + i;
        int e = e_loc[i];
        int pos = cur[e]++;
        pair_ts[pos] = p;          // t = p>>1, k = p&1
        pair_w[pos]  = tw[p];
    }
}

// ---------------- grouped GEMM tiles --------------------------------------
#define BM 64
#define BN 64
#define BK 64
#define LDK (BK + 8)   // +16B row pad: breaks the 128B-stride bank conflict

// GEMM1: C1[q, 0:1024] = X[token(q), :] @ W1[e]   (K = H_ = 1024)
__global__ __launch_bounds__(256) void gemm1_kernel(
    const float* __restrict__ X, const float* __restrict__ W1,
    const int* __restrict__ offs, const int* __restrict__ pair_ts,
    float* __restrict__ c1)
{
    const int e    = blockIdx.z;
    const int rbeg = offs[e], rend = offs[e + 1];
    const int ne   = rend - rbeg;
    const int row0 = blockIdx.y * BM;
    if (row0 >= ne) return;
    const int col0 = blockIdx.x * BN;

    __shared__ unsigned short As[BM][LDK];
    __shared__ unsigned short Bs[BN][LDK];

    const int tid = threadIdx.x;
    const float* W1e = W1 + (size_t)e * H_ * (2 * I_);

    // tokens for the 4 A-rows this thread stages (clamped for tail rows)
    int trow[4];
    {
        int rb = tid >> 4;
        for (int i = 0; i < 4; ++i) {
            int q = rbeg + row0 + rb + i * 16;
            if (q > rend - 1) q = rend - 1;
            trow[i] = pair_ts[q] >> 1;
        }
    }

    f32x4 acc[2][2];
    for (int m = 0; m < 2; ++m)
        for (int n = 0; n < 2; ++n)
            acc[m][n] = f32x4{0.f, 0.f, 0.f, 0.f};

    const int lane = tid & 63;
    const int w    = tid >> 6;
    const int wr = w >> 1, wc = w & 1;
    const int lrow = lane & 15;
    const int lk   = lane >> 4;

    for (int kt = 0; kt < H_ / BK; ++kt) {
        const int kbase = kt * BK;
        // stage A (gathered X rows, fp32 -> bf16)
        {
            int rb = tid >> 4;
            int c  = (tid & 15) * 4;
            for (int i = 0; i < 4; ++i) {
                int r = rb + i * 16;
                const float4 x = *(const float4*)&X[(size_t)trow[i] * H_ + kbase + c];
                ushort4 b; b.x = f2bf(x.x); b.y = f2bf(x.y); b.z = f2bf(x.z); b.w = f2bf(x.w);
                *(ushort4*)&As[r][c] = b;
            }
        }
        // stage B transposed (W1 row-major [k][n] -> Bs[n][k])
        {
            int kb = tid >> 4;
            int c  = (tid & 15) * 4;
            for (int i = 0; i < 4; ++i) {
                int k = kb + i * 16;
                const float4 x = *(const float4*)&W1e[(size_t)(kbase + k) * (2 * I_) + col0 + c];
                Bs[c + 0][k] = f2bf(x.x);
                Bs[c + 1][k] = f2bf(x.y);
                Bs[c + 2][k] = f2bf(x.z);
                Bs[c + 3][k] = f2bf(x.w);
            }
        }
        __syncthreads();
        for (int kk = 0; kk < BK; kk += 32) {
            bf16x8 af[2], bfr[2];
            for (int m = 0; m < 2; ++m)
                af[m] = *(const bf16x8*)&As[wr * 32 + m * 16 + lrow][kk + lk * 8];
            for (int n = 0; n < 2; ++n)
                bfr[n] = *(const bf16x8*)&Bs[wc * 32 + n * 16 + lrow][kk + lk * 8];
            for (int m = 0; m < 2; ++m)
                for (int n = 0; n < 2; ++n)
                    acc[m][n] = __builtin_amdgcn_mfma_f32_16x16x32_bf16(af[m], bfr[n], acc[m][n], 0, 0, 0);
        }
        __syncthreads();
    }

    // epilogue: D layout col=lane&15, row=(lane>>4)*4+reg (measured)
    for (int m = 0; m < 2; ++m) {
        for (int reg = 0; reg < 4; ++reg) {
            int rloc = wr * 32 + m * 16 + lk * 4 + reg;
            if (row0 + rloc < ne) {
                int q = rbeg + row0 + rloc;
                for (int n = 0; n < 2; ++n) {
                    int cg = col0 + wc * 32 + n * 16 + lrow;
                    c1[(size_t)q * (2 * I_) + cg] = acc[m][n][reg];
                }
            }
        }
    }
}

// ---------------- activation: act = bf16(silu(gate) * up) ------------------
__global__ __launch_bounds__(256) void act_kernel(
    const float* __restrict__ c1, unsigned short* __restrict__ act)
{
    int idx = blockIdx.x * blockDim.x + threadIdx.x;   // NPAIR*I_/4 threads
    int i0 = (idx * 4) & (I_ - 1);
    int q  = (idx * 4) >> 9;
    const float4 g = *(const float4*)&c1[(size_t)q * (2 * I_) + i0];
    const float4 u = *(const float4*)&c1[(size_t)q * (2 * I_) + I_ + i0];
    ushort4 o;
    o.x = f2bf(g.x / (1.f + __expf(-g.x)) * u.x);
    o.y = f2bf(g.y / (1.f + __expf(-g.y)) * u.y);
    o.z = f2bf(g.z / (1.f + __expf(-g.z)) * u.z);
    o.w = f2bf(g.w / (1.f + __expf(-g.w)) * u.w);
    *(ushort4*)&act[(size_t)q * I_ + i0] = o;
}

// GEMM2: out[t, :] += w * (act[q, :] @ W2[e])   (K = I_ = 512)
__global__ __launch_bounds__(256) void gemm2_kernel(
    const unsigned short* __restrict__ act, const float* __restrict__ W2,
    const int* __restrict__ offs, const int* __restrict__ pair_ts,
    const float* __restrict__ pair_w, float* __restrict__ out)
{
    const int e    = blockIdx.z;
    const int rbeg = offs[e], rend = offs[e + 1];
    const int ne   = rend - rbeg;
    const int row0 = blockIdx.y * BM;
    if (row0 >= ne) return;
    const int col0 = blockIdx.x * BN;

    __shared__ unsigned short As[BM][LDK];
    __shared__ unsigned short Bs[BN][LDK];

    const int tid = threadIdx.x;
    const float* W2e = W2 + (size_t)e * I_ * H_;

    f32x4 acc[2][2];
    for (int m = 0; m < 2; ++m)
        for (int n = 0; n < 2; ++n)
            acc[m][n] = f32x4{0.f, 0.f, 0.f, 0.f};

    const int lane = tid & 63;
    const int w    = tid >> 6;
    const int wr = w >> 1, wc = w & 1;
    const int lrow = lane & 15;
    const int lk   = lane >> 4;

    for (int kt = 0; kt < I_ / BK; ++kt) {
        const int kbase = kt * BK;
        // stage A (act rows already bf16, contiguous per expert)
        {
            int rb = tid >> 3;          // 0..31
            int c8 = (tid & 7) * 8;     // 8 ushorts = 16B
            for (int i = 0; i < 2; ++i) {
                int r = rb + i * 32;
                int q = rbeg + row0 + r;
                if (q > NPAIR - 1) q = NPAIR - 1;
                const uint4 x = *(const uint4*)&act[(size_t)q * I_ + kbase + c8];
                *(uint4*)&As[r][c8] = x;
            }
        }
        // stage B transposed (W2 [k][n] -> Bs[n][k])
        {
            int kb = tid >> 4;
            int c  = (tid & 15) * 4;
            for (int i = 0; i < 4; ++i) {
                int k = kb + i * 16;
                const float4 x = *(const float4*)&W2e[(size_t)(kbase + k) * H_ + col0 + c];
                Bs[c + 0][k] = f2bf(x.x);
                Bs[c + 1][k] = f2bf(x.y);
                Bs[c + 2][k] = f2bf(x.z);
                Bs[c + 3][k] = f2bf(x.w);
            }
        }
        __syncthreads();
        for (int kk = 0; kk < BK; kk += 32) {
            bf16x8 af[2], bfr[2];
            for (int m = 0; m < 2; ++m)
                af[m] = *(const bf16x8*)&As[wr * 32 + m * 16 + lrow][kk + lk * 8];
            for (int n = 0; n < 2; ++n)
                bfr[n] = *(const bf16x8*)&Bs[wc * 32 + n * 16 + lrow][kk + lk * 8];
            for (int m = 0; m < 2; ++m)
                for (int n = 0; n < 2; ++n)
                    acc[m][n] = __builtin_amdgcn_mfma_f32_16x16x32_bf16(af[m], bfr[n], acc[m][n], 0, 0, 0);
        }
        __syncthreads();
    }

    for (int m = 0; m < 2; ++m) {
        for (int reg = 0; reg < 4; ++reg) {
            int rloc = wr * 32 + m * 16 + lk * 4 + reg;
            if (row0 + rloc < ne) {
                int q   = rbeg + row0 + rloc;
                int t   = pair_ts[q] >> 1;
                float wg = pair_w[q];
                for (int n = 0; n < 2; ++n) {
                    int cg = col0 + wc * 32 + n * 16 + lrow;
                    atomicAdd(&out[(size_t)t * H_ + cg], wg * acc[m][n][reg]);
                }
            }
        }
    }
}

extern "C" void kernel_launch(void* const* d_in, const int* in_sizes, int n_in,
                              void* d_out, int out_size, void* d_ws, size_t ws_size,
                              hipStream_t stream)
{
    const float* X  = (const float*)d_in[0];   // [T,H]
    const float* tw = (const float*)d_in[1];   // [T,K]
    const int*   ti = (const int*)d_in[2];     // [T,K]
    const float* W1 = (const float*)d_in[3];   // [E,H,2I]
    const float* W2 = (const float*)d_in[4];   // [E,I,H]
    float* out = (float*)d_out;                // [T,H] fp32

    char* ws = (char*)d_ws;
    int*   offs    = (int*)(ws);
    int*   pair_ts = (int*)(ws + 1024);
    float* pair_w  = (float*)(ws + 1024 + NPAIR * 4);
    float* c1      = (float*)(ws + (1u << 20));
    unsigned short* act = (unsigned short*)(ws + (1u << 20) + (size_t)NPAIR * (2 * I_) * 4);

    hipMemsetAsync(d_out, 0, (size_t)out_size * sizeof(float), stream);

    route_kernel<<<1, 256, 0, stream>>>(tw, ti, offs, pair_ts, pair_w);

    gemm1_kernel<<<dim3((2 * I_) / BN, NPAIR / BM, E_), 256, 0, stream>>>(X, W1, offs, pair_ts, c1);

    act_kernel<<<(NPAIR * I_ / 4) / 256, 256, 0, stream>>>(c1, act);

    gemm2_kernel<<<dim3(H_ / BN, NPAIR / BM, E_), 256, 0, stream>>>(act, W2, offs, pair_ts, pair_w, out);
}

// Round 2
// 97.114 us; speedup vs baseline: 1.3058x; 1.3058x over previous
//
#include <hip/hip_runtime.h>

// MoE experts: route -> gather(bf16) -> grouped GEMM1+silu -> grouped GEMM2 -> atomic combine
#define E_ 16
#define T_ 2048
#define H_ 1024
#define I_ 512
#define K_ 2
#define NPAIR (T_*K_)          // 4096 token-expert pairs

typedef __bf16 bf16x8 __attribute__((ext_vector_type(8)));
typedef float  f32x4  __attribute__((ext_vector_type(4)));

static __device__ __forceinline__ unsigned short f2bf(float f) {
    __bf16 h = (__bf16)f;                       // RNE convert
    return __builtin_bit_cast(unsigned short, h);
}

// ---------------- routing: stable counting sort of 4096 pairs by expert ----
__global__ __launch_bounds__(256) void route_kernel(
    const float* __restrict__ tw, const int* __restrict__ ti,
    int* __restrict__ offs, int* __restrict__ pair_ts, float* __restrict__ pair_w)
{
    __shared__ unsigned short hist[256][E_];
    __shared__ int ebase[E_];
    const int tid = threadIdx.x;

    int e_loc[16];
    unsigned short h[E_];
    for (int e = 0; e < E_; ++e) h[e] = 0;
    for (int i = 0; i < 16; ++i) {
        int p = tid * 16 + i;
        int e = ti[p];
        e_loc[i] = e;
        h[e]++;
    }
    for (int e = 0; e < E_; ++e) hist[tid][e] = h[e];
    __syncthreads();

    if (tid < E_) {
        int e = tid, run = 0;
        for (int t = 0; t < 256; ++t) {
            unsigned short c = hist[t][e];
            hist[t][e] = (unsigned short)run;
            run += c;
        }
        ebase[e] = run;
    }
    __syncthreads();
    if (tid == 0) {
        int run = 0;
        for (int e = 0; e < E_; ++e) { int c = ebase[e]; offs[e] = run; ebase[e] = run; run += c; }
        offs[E_] = run;
    }
    __syncthreads();

    int cur[E_];
    for (int e = 0; e < E_; ++e) cur[e] = ebase[e] + hist[tid][e];
    for (int i = 0; i < 16; ++i) {
        int p = tid * 16 + i;
        int e = e_loc[i];
        int pos = cur[e]++;
        pair_ts[pos] = p;          // t = p>>1
        pair_w[pos]  = tw[p];
    }
}

// ---------------- gather: Ag[q][:] = bf16(X[token(q)][:]) ------------------
__global__ __launch_bounds__(256) void gather_kernel(
    const float* __restrict__ X, const int* __restrict__ pair_ts,
    unsigned short* __restrict__ Ag)
{
    const int q = blockIdx.x;
    const int t = pair_ts[q] >> 1;
    const int c = threadIdx.x * 4;
    const float4 x = *(const float4*)&X[(size_t)t * H_ + c];
    ushort4 b; b.x = f2bf(x.x); b.y = f2bf(x.y); b.z = f2bf(x.z); b.w = f2bf(x.w);
    *(ushort4*)&Ag[(size_t)q * H_ + c] = b;
}

// ---------------- grouped GEMM1 + fused silu-gate --------------------------
// BM=256 rows, cols: 32 gate + 32 up (fused), BK=64, 4 waves each 64x64 output.
#define LDK 70   // row stride 140B = 35 words == 3 banks (mod 32): <=2-way everywhere

__global__ __launch_bounds__(256) void gemm1_kernel(
    const unsigned short* __restrict__ Ag, const float* __restrict__ W1,
    const int* __restrict__ offs, unsigned short* __restrict__ act)
{
    const int e    = blockIdx.z;
    const int rbeg = offs[e], rend = offs[e + 1];
    const int ne   = rend - rbeg;
    const int row0 = blockIdx.y * 256;
    if (row0 >= ne) return;
    const int c0 = blockIdx.x * 32;          // gate col block; up cols = I_ + c0

    __shared__ unsigned short As[256][LDK];  // 35 KB
    __shared__ unsigned short Bs[64][LDK];   // 8.75 KB

    const int tid = threadIdx.x;
    const float* __restrict__ W1e = W1 + (size_t)e * H_ * (2 * I_);

    // A-staging geometry: 8 lanes per row, 16B each; 8 row-passes
    const int ar = tid >> 3;          // 0..31
    const int ac = (tid & 7) * 8;     // bf16 offset
    int aq[8];
    for (int i = 0; i < 8; ++i) {
        int q = rbeg + row0 + ar + i * 32;
        aq[i] = q < rend ? q : rend - 1;
    }

    // B-staging geometry: lane-major-n (64 n's), 4 k-slices of 16
    const int bn   = tid & 63;
    const int bks  = tid >> 6;        // 0..3
    const int bcol = (bn < 32) ? (c0 + bn) : (I_ + c0 + (bn - 32));

    f32x4 acc[4][4];
    for (int m = 0; m < 4; ++m)
        for (int n = 0; n < 4; ++n)
            acc[m][n] = f32x4{0.f, 0.f, 0.f, 0.f};

    const int lane = tid & 63;
    const int w    = tid >> 6;
    const int lrow = lane & 15;
    const int lk   = lane >> 4;

    for (int kt = 0; kt < H_ / 64; ++kt) {
        const int kb = kt * 64;
        // stage A (bf16, contiguous)
        #pragma unroll
        for (int i = 0; i < 8; ++i) {
            const uint4 x = *(const uint4*)&Ag[(size_t)aq[i] * H_ + kb + ac];
            *(uint4*)&As[ar + i * 32][ac] = x;
        }
        // stage B: 16 k-strided dwords (coalesced along n), contiguous row writes
        {
            float v[16];
            #pragma unroll
            for (int i = 0; i < 16; ++i)
                v[i] = W1e[(size_t)(kb + bks * 16 + i) * (2 * I_) + bcol];
            #pragma unroll
            for (int i = 0; i < 16; i += 4) {
                ushort4 p;
                p.x = f2bf(v[i]); p.y = f2bf(v[i+1]); p.z = f2bf(v[i+2]); p.w = f2bf(v[i+3]);
                *(ushort4*)&Bs[bn][bks * 16 + i] = p;
            }
        }
        __syncthreads();
        #pragma unroll
        for (int kk = 0; kk < 64; kk += 32) {
            bf16x8 af[4], bfr[4];
            #pragma unroll
            for (int m = 0; m < 4; ++m)
                af[m] = *(const bf16x8*)&As[w * 64 + m * 16 + lrow][kk + lk * 8];
            #pragma unroll
            for (int n = 0; n < 4; ++n)
                bfr[n] = *(const bf16x8*)&Bs[n * 16 + lrow][kk + lk * 8];
            #pragma unroll
            for (int m = 0; m < 4; ++m)
                #pragma unroll
                for (int n = 0; n < 4; ++n)
                    acc[m][n] = __builtin_amdgcn_mfma_f32_16x16x32_bf16(af[m], bfr[n], acc[m][n], 0, 0, 0);
        }
        __syncthreads();
    }

    // epilogue: act[q][c0 + fn*16 + lrow] = silu(gate)*up  (gate frag fn, up frag fn+2)
    for (int m = 0; m < 4; ++m) {
        for (int reg = 0; reg < 4; ++reg) {
            int rloc = w * 64 + m * 16 + lk * 4 + reg;
            if (row0 + rloc < ne) {
                int q = rbeg + row0 + rloc;
                #pragma unroll
                for (int fn = 0; fn < 2; ++fn) {
                    float g = acc[m][fn][reg];
                    float u = acc[m][fn + 2][reg];
                    float a = g / (1.f + __expf(-g)) * u;
                    act[(size_t)q * I_ + c0 + fn * 16 + lrow] = f2bf(a);
                }
            }
        }
    }
}

// ---------------- grouped GEMM2 + weighted atomic combine ------------------
// BM=256 rows, BN=64 cols of H, BK=64 over K=I_=512.
__global__ __launch_bounds__(256) void gemm2_kernel(
    const unsigned short* __restrict__ act, const float* __restrict__ W2,
    const int* __restrict__ offs, const int* __restrict__ pair_ts,
    const float* __restrict__ pair_w, float* __restrict__ out)
{
    const int e    = blockIdx.z;
    const int rbeg = offs[e], rend = offs[e + 1];
    const int ne   = rend - rbeg;
    const int row0 = blockIdx.y * 256;
    if (row0 >= ne) return;
    const int c0 = blockIdx.x * 64;

    __shared__ unsigned short As[256][LDK];
    __shared__ unsigned short Bs[64][LDK];

    const int tid = threadIdx.x;
    const float* __restrict__ W2e = W2 + (size_t)e * I_ * H_;

    const int ar = tid >> 3;
    const int ac = (tid & 7) * 8;
    int aq[8];
    for (int i = 0; i < 8; ++i) {
        int q = rbeg + row0 + ar + i * 32;
        aq[i] = q < rend ? q : rend - 1;
    }

    const int bn  = tid & 63;
    const int bks = tid >> 6;

    f32x4 acc[4][4];
    for (int m = 0; m < 4; ++m)
        for (int n = 0; n < 4; ++n)
            acc[m][n] = f32x4{0.f, 0.f, 0.f, 0.f};

    const int lane = tid & 63;
    const int w    = tid >> 6;
    const int lrow = lane & 15;
    const int lk   = lane >> 4;

    for (int kt = 0; kt < I_ / 64; ++kt) {
        const int kb = kt * 64;
        #pragma unroll
        for (int i = 0; i < 8; ++i) {
            const uint4 x = *(const uint4*)&act[(size_t)aq[i] * I_ + kb + ac];
            *(uint4*)&As[ar + i * 32][ac] = x;
        }
        {
            float v[16];
            #pragma unroll
            for (int i = 0; i < 16; ++i)
                v[i] = W2e[(size_t)(kb + bks * 16 + i) * H_ + c0 + bn];
            #pragma unroll
            for (int i = 0; i < 16; i += 4) {
                ushort4 p;
                p.x = f2bf(v[i]); p.y = f2bf(v[i+1]); p.z = f2bf(v[i+2]); p.w = f2bf(v[i+3]);
                *(ushort4*)&Bs[bn][bks * 16 + i] = p;
            }
        }
        __syncthreads();
        #pragma unroll
        for (int kk = 0; kk < 64; kk += 32) {
            bf16x8 af[4], bfr[4];
            #pragma unroll
            for (int m = 0; m < 4; ++m)
                af[m] = *(const bf16x8*)&As[w * 64 + m * 16 + lrow][kk + lk * 8];
            #pragma unroll
            for (int n = 0; n < 4; ++n)
                bfr[n] = *(const bf16x8*)&Bs[n * 16 + lrow][kk + lk * 8];
            #pragma unroll
            for (int m = 0; m < 4; ++m)
                #pragma unroll
                for (int n = 0; n < 4; ++n)
                    acc[m][n] = __builtin_amdgcn_mfma_f32_16x16x32_bf16(af[m], bfr[n], acc[m][n], 0, 0, 0);
        }
        __syncthreads();
    }

    for (int m = 0; m < 4; ++m) {
        for (int reg = 0; reg < 4; ++reg) {
            int rloc = w * 64 + m * 16 + lk * 4 + reg;
            if (row0 + rloc < ne) {
                int q   = rbeg + row0 + rloc;
                int t   = pair_ts[q] >> 1;
                float wt = pair_w[q];
                #pragma unroll
                for (int fn = 0; fn < 4; ++fn) {
                    int cg = c0 + fn * 16 + lrow;
                    atomicAdd(&out[(size_t)t * H_ + cg], wt * acc[m][fn][reg]);
                }
            }
        }
    }
}

extern "C" void kernel_launch(void* const* d_in, const int* in_sizes, int n_in,
                              void* d_out, int out_size, void* d_ws, size_t ws_size,
                              hipStream_t stream)
{
    const float* X  = (const float*)d_in[0];   // [T,H]
    const float* tw = (const float*)d_in[1];   // [T,K]
    const int*   ti = (const int*)d_in[2];     // [T,K]
    const float* W1 = (const float*)d_in[3];   // [E,H,2I]
    const float* W2 = (const float*)d_in[4];   // [E,I,H]
    float* out = (float*)d_out;                // [T,H] fp32

    char* ws = (char*)d_ws;
    int*   offs    = (int*)(ws);
    int*   pair_ts = (int*)(ws + 256);
    float* pair_w  = (float*)(ws + 256 + NPAIR * 4);
    unsigned short* Ag  = (unsigned short*)(ws + (1u << 16));                       // 8 MiB
    unsigned short* act = (unsigned short*)(ws + (1u << 16) + (size_t)NPAIR * H_ * 2); // 4 MiB

    hipMemsetAsync(d_out, 0, (size_t)out_size * sizeof(float), stream);

    route_kernel<<<1, 256, 0, stream>>>(tw, ti, offs, pair_ts, pair_w);

    gather_kernel<<<NPAIR, 256, 0, stream>>>(X, pair_ts, Ag);

    gemm1_kernel<<<dim3(I_ / 32, NPAIR / 256, E_), 256, 0, stream>>>(Ag, W1, offs, act);

    gemm2_kernel<<<dim3(H_ / 64, NPAIR / 256, E_), 256, 0, stream>>>(act, W2, offs, pair_ts, pair_w, out);
}